// Round 3
// baseline (1149.068 us; speedup 1.0000x reference)
//
#include <hip/hip_runtime.h>
#include <hip/hip_bf16.h>
#include <hip/hip_fp16.h>

#define T_ 2048
#define B_ 64
#define NIN_ 128
#define H_ 256
#define NOUT_ 128
#define TB_ (T_*B_)
#define BH_ (B_*H_)
#define TBLK_ (T_/8)   // 256 blocks of 8 timesteps

typedef _Float16 h8 __attribute__((ext_vector_type(8)));
typedef _Float16 h4 __attribute__((ext_vector_type(4)));
typedef _Float16 h2 __attribute__((ext_vector_type(2)));
typedef float f32x4 __attribute__((ext_vector_type(4)));

// LDS-only barrier: do NOT drain vmcnt (global loads/stores stay in flight).
#define BAR_LGKM() asm volatile("s_waitcnt lgkmcnt(0)\n\ts_barrier" ::: "memory")

// extract f16 pair p (elements 2p,2p+1) from an h8 as an h2 (sub-register view)
#define PK2(v,p) __builtin_shufflevector((v), (v), 2*(p), 2*(p)+1)

__device__ __forceinline__ h8 cvt8(float4 a, float4 b) {
    h8 r;
    r[0] = (_Float16)a.x; r[1] = (_Float16)a.y; r[2] = (_Float16)a.z; r[3] = (_Float16)a.w;
    r[4] = (_Float16)b.x; r[5] = (_Float16)b.y; r[6] = (_Float16)b.z; r[7] = (_Float16)b.w;
    return r;
}
__device__ __forceinline__ h8 ld_cvt8(const float* __restrict__ p) {
    const float4* q = (const float4*)p;
    return cvt8(q[0], q[1]);
}

// ---------------------------------------------------------------------------
// K1: xp2[b][t/8][j][t%8] (f16) = x[t][b][:] @ W_ih^T + (b_ih+b_hh)
// (unchanged from proven baseline)
// ---------------------------------------------------------------------------
__global__ __launch_bounds__(256, 2) void k1_xproj(
    const float* __restrict__ x,
    const float* __restrict__ w_ih,
    const float* __restrict__ b_ih,
    const float* __restrict__ b_hh,
    _Float16* __restrict__ xp2)
{
    const int tid = threadIdx.x;
    const int lane = tid & 63, wave = tid >> 6;
    const int m = lane & 15, quad = lane >> 4;
    const int b  = blockIdx.x >> 4;
    const int tc = blockIdx.x & 15;

    h8 af[4][4];
    #pragma unroll
    for (int i = 0; i < 4; ++i)
        #pragma unroll
        for (int kt = 0; kt < 4; ++kt)
            af[i][kt] = ld_cvt8(w_ih + (size_t)(wave*64 + i*16 + m) * NIN_ + kt*32 + quad*8);

    float bias[4][4];
    #pragma unroll
    for (int i = 0; i < 4; ++i)
        #pragma unroll
        for (int r = 0; r < 4; ++r) {
            int c = wave*64 + i*16 + quad*4 + r;
            bias[i][r] = b_ih[c] + b_hh[c];
        }

    __shared__ __align__(16) _Float16 st2[2][256 * 24];   // [j][t] stride 24

    float4 xr[4][2];
    {
        const int t0 = tc * 128;
        #pragma unroll
        for (int kt = 0; kt < 4; ++kt) {
            const float4* q = (const float4*)(x + ((size_t)(t0 + m) * B_ + b) * NIN_ + kt*32 + quad*8);
            xr[kt][0] = q[0]; xr[kt][1] = q[1];
        }
    }

    for (int rt = 0; rt < 8; ++rt) {
        const int t0 = tc * 128 + rt * 16;

        h8 bf[4];
        #pragma unroll
        for (int kt = 0; kt < 4; ++kt) bf[kt] = cvt8(xr[kt][0], xr[kt][1]);

        if (rt < 7) {
            #pragma unroll
            for (int kt = 0; kt < 4; ++kt) {
                const float4* q = (const float4*)(x + ((size_t)(t0 + 16 + m) * B_ + b) * NIN_ + kt*32 + quad*8);
                xr[kt][0] = q[0]; xr[kt][1] = q[1];
            }
        }

        f32x4 acc[4];
        #pragma unroll
        for (int i = 0; i < 4; ++i) acc[i] = (f32x4){0,0,0,0};
        #pragma unroll
        for (int i = 0; i < 4; ++i)
            #pragma unroll
            for (int kt = 0; kt < 4; ++kt)
                acc[i] = __builtin_amdgcn_mfma_f32_16x16x32_f16(af[i][kt], bf[kt], acc[i], 0, 0, 0);

        const int p = rt & 1;
        #pragma unroll
        for (int i = 0; i < 4; ++i)
            #pragma unroll
            for (int r = 0; r < 4; ++r) {
                int j = wave*64 + i*16 + quad*4 + r;
                st2[p][j*24 + m] = (_Float16)(acc[i][r] + bias[i][r]);
            }
        BAR_LGKM();
        {
            const int j = tid;
            const h8* row = (const h8*)&st2[p][j*24];
            h8 v0 = row[0], v1 = row[1];
            const int blk = t0 >> 3;
            _Float16* dst = xp2 + ((size_t)(b * TBLK_ + blk) * H_ + j) * 8;
            *(h8*)dst            = v0;
            *(h8*)(dst + H_*8)   = v1;
        }
    }
}

// ---------------------------------------------------------------------------
// K2: sequential scan, hybrid MFMA + VALU.
// The 8-wave lockstep structure's step = MFMA-pipe (per-SIMD) + ~350 cyc
// exposed serial latency. Per-SIMD pipe is cut 620->388 cyc by offloading
// K-chunks 5..7 (k=160..255) to the VALU (v_pk_fma_f16), which co-schedules
// with the matrix pipe (m114) and is otherwise ~75% idle.
//   - VALU tail consumes the SAME av[5..7] LDS fragments the MFMA path
//     would have used (slice `quad` of each chunk) -> zero extra LDS traffic.
//   - each lane runs two 12-pair pk-dot chains (columns n and n+16 of its
//     wave), then a 2-stage __shfl_xor(16/32) butterfly sums the four
//     quad-slices per column. All hidden under the 388-cyc MFMA phase,
//     even if pk_fma is far below full rate (latency-tolerant by design).
//   - f32 accumulator via MFMA for k<160; f16x2 chains (<=12 terms) for the
//     tail -> adds <~2e-4 absolute error.
// Everything else (xp2 prefetch, double-buffered h LDS, 1 lgkm-only
// barrier/step, quads 2-3 duplicate) identical to the proven kernel.
// ---------------------------------------------------------------------------
__global__ __launch_bounds__(512, 1) void k2_scan(
    const _Float16* __restrict__ xp2,      // [B][T/8][H][8] f16
    const float* __restrict__ w_hh,        // [H][H] f32
    _Float16* __restrict__ hs)             // [T][B][H] f16
{
    const int tid = threadIdx.x;
    const int lane = tid & 63, wave = tid >> 6;   // wave 0..7
    const int n = lane & 15, quad = lane >> 4;
    const int b = blockIdx.x;
    const int tsel = quad & 1;                    // which of the wave's 2 N-tiles
    const int j = wave*32 + tsel*16 + n;          // owned output column
    const bool writer = (quad < 2);               // quads 2,3 duplicate 0,1

    // B-frags (W_hh) for MFMA K-chunks 0..4: 2 tiles x 5 K-steps, 40 VGPRs
    h8 bf[2][5];
    #pragma unroll
    for (int t = 0; t < 2; ++t)
        #pragma unroll
        for (int kt = 0; kt < 5; ++kt)
            bf[t][kt] = ld_cvt8(w_hh + (size_t)(wave*32 + t*16 + n) * H_ + kt*32 + quad*8);

    // VALU tail weights, chunks 5..7 slice `quad`, for columns A=wave*32+n, B=A+16
    h8 wA[3], wB[3];
    #pragma unroll
    for (int c = 0; c < 3; ++c) {
        wA[c] = ld_cvt8(w_hh + (size_t)(wave*32 + n)      * H_ + (5+c)*32 + quad*8);
        wB[c] = ld_cvt8(w_hh + (size_t)(wave*32 + 16 + n) * H_ + (5+c)*32 + quad*8);
    }

    __shared__ __align__(16) _Float16 hb[2][256];
    if (tid < 256) hb[0][tid] = (_Float16)0.0f;
    __syncthreads();

    const _Float16* xq = xp2 + ((size_t)b * TBLK_ * H_ + j) * 8;
    _Float16*       hsl = hs + (size_t)b * H_ + j;

    h8 pf = *(const h8*)xq;                 // block 0

#define K2_STEP(T, RB, WB, XV)                                                 \
    {                                                                          \
        const h8* hp = (const h8*)&RB[0];                                      \
        h8 av[8];                                                              \
        _Pragma("unroll")                                                      \
        for (int kt = 0; kt < 8; ++kt) av[kt] = hp[kt*4 + quad];               \
        f32x4 acc[2];                                                          \
        acc[0] = (f32x4){0,0,0,0}; acc[1] = (f32x4){0,0,0,0};                  \
        _Pragma("unroll")                                                      \
        for (int kt = 0; kt < 5; ++kt) {                                       \
            acc[0] = __builtin_amdgcn_mfma_f32_16x16x32_f16(av[kt], bf[0][kt], acc[0], 0, 0, 0); \
            acc[1] = __builtin_amdgcn_mfma_f32_16x16x32_f16(av[kt], bf[1][kt], acc[1], 0, 0, 0); \
        }                                                                      \
        h2 aA0 = (h2){0,0}, aA1 = (h2){0,0}, aB0 = (h2){0,0}, aB1 = (h2){0,0}; \
        _Pragma("unroll")                                                      \
        for (int c = 0; c < 3; ++c) {                                          \
            h8 hv = av[5+c];                                                   \
            aA0 = PK2(hv,0)*PK2(wA[c],0) + aA0;                                \
            aA1 = PK2(hv,1)*PK2(wA[c],1) + aA1;                                \
            aA0 = PK2(hv,2)*PK2(wA[c],2) + aA0;                                \
            aA1 = PK2(hv,3)*PK2(wA[c],3) + aA1;                                \
            aB0 = PK2(hv,0)*PK2(wB[c],0) + aB0;                                \
            aB1 = PK2(hv,1)*PK2(wB[c],1) + aB1;                                \
            aB0 = PK2(hv,2)*PK2(wB[c],2) + aB0;                                \
            aB1 = PK2(hv,3)*PK2(wB[c],3) + aB1;                                \
        }                                                                      \
        float pA = ((float)aA0[0] + (float)aA0[1]) + ((float)aA1[0] + (float)aA1[1]); \
        float pB = ((float)aB0[0] + (float)aB0[1]) + ((float)aB1[0] + (float)aB1[1]); \
        pA += __shfl_xor(pA, 16, 64);                                          \
        pA += __shfl_xor(pA, 32, 64);                                          \
        pB += __shfl_xor(pB, 16, 64);                                          \
        pB += __shfl_xor(pB, 32, 64);                                          \
        float vv = tsel ? acc[1][0] : acc[0][0];                               \
        float vt = tsel ? pB : pA;                                             \
        float sv = vv + vt + (XV);                                             \
        float e  = __expf(2.0f * sv);                                          \
        float hn = fmaf(-2.0f, __builtin_amdgcn_rcpf(e + 1.0f), 1.0f);         \
        _Float16 h16 = (_Float16)hn;                                           \
        if (writer) {                                                          \
            WB[j] = h16;                                                       \
            hsl[(size_t)(T) * BH_] = h16;                                      \
        }                                                                      \
        BAR_LGKM();                                                            \
    }

    for (int tb = 0; tb < TBLK_; ++tb) {
        h8 cur = pf;                         // waits on load issued 1 block ago
        const int tnb = (tb + 1 < TBLK_) ? tb + 1 : TBLK_ - 1;
        pf = *(const h8*)(xq + (size_t)tnb * (H_ * 8));   // in flight for 8 steps
        const int t = tb * 8;
        K2_STEP(t + 0, hb[0], hb[1], (float)cur[0])
        K2_STEP(t + 1, hb[1], hb[0], (float)cur[1])
        K2_STEP(t + 2, hb[0], hb[1], (float)cur[2])
        K2_STEP(t + 3, hb[1], hb[0], (float)cur[3])
        K2_STEP(t + 4, hb[0], hb[1], (float)cur[4])
        K2_STEP(t + 5, hb[1], hb[0], (float)cur[5])
        K2_STEP(t + 6, hb[0], hb[1], (float)cur[6])
        K2_STEP(t + 7, hb[1], hb[0], (float)cur[7])
    }
#undef K2_STEP
}

// ---------------------------------------------------------------------------
// K3: out[TB][128](f32) = hs[TB][256](f16) @ W_out^T + b_out   (MFMA C^T)
// (unchanged from proven baseline)
// ---------------------------------------------------------------------------
__global__ __launch_bounds__(256, 2) void k3_out(
    const _Float16* __restrict__ hs,
    const float* __restrict__ w_out,
    const float* __restrict__ b_out,
    float* __restrict__ out)
{
    const int tid = threadIdx.x;
    const int lane = tid & 63, wave = tid >> 6;
    const int m = lane & 15, quad = lane >> 4;

    h8 af[2][8];
    #pragma unroll
    for (int i = 0; i < 2; ++i)
        #pragma unroll
        for (int kt = 0; kt < 8; ++kt)
            af[i][kt] = ld_cvt8(w_out + (size_t)(wave*32 + i*16 + m) * H_ + kt*32 + quad*8);

    float bias[2][4];
    #pragma unroll
    for (int i = 0; i < 2; ++i)
        #pragma unroll
        for (int r = 0; r < 4; ++r)
            bias[i][r] = b_out[wave*32 + i*16 + quad*4 + r];

    __shared__ __align__(16) float st[2][16][132];

    h8 bf[8];
    {
        const size_t n0 = (size_t)blockIdx.x * 128;
        #pragma unroll
        for (int kt = 0; kt < 8; ++kt)
            bf[kt] = *(const h8*)(hs + (n0 + m) * H_ + kt*32 + quad*8);
    }

    for (int rt = 0; rt < 8; ++rt) {
        const size_t n0 = (size_t)blockIdx.x * 128 + rt * 16;

        h8 cur[8];
        #pragma unroll
        for (int kt = 0; kt < 8; ++kt) cur[kt] = bf[kt];

        if (rt < 7) {
            #pragma unroll
            for (int kt = 0; kt < 8; ++kt)
                bf[kt] = *(const h8*)(hs + (n0 + 16 + m) * H_ + kt*32 + quad*8);
        }

        f32x4 acc[2];
        #pragma unroll
        for (int i = 0; i < 2; ++i) acc[i] = (f32x4){0,0,0,0};
        #pragma unroll
        for (int i = 0; i < 2; ++i)
            #pragma unroll
            for (int kt = 0; kt < 8; ++kt)
                acc[i] = __builtin_amdgcn_mfma_f32_16x16x32_f16(af[i][kt], cur[kt], acc[i], 0, 0, 0);

        const int p = rt & 1;
        #pragma unroll
        for (int i = 0; i < 2; ++i) {
            f32x4 v;
            #pragma unroll
            for (int r = 0; r < 4; ++r) v[r] = acc[i][r] + bias[i][r];
            *(f32x4*)&st[p][m][wave*32 + i*16 + quad*4] = v;
        }
        BAR_LGKM();
        #pragma unroll
        for (int it = 0; it < 2; ++it) {
            int idx = tid + it*256;
            int r = idx >> 5, c4 = (idx & 31) * 4;
            f32x4 v = *(const f32x4*)&st[p][r][c4];
            *(f32x4*)(out + (n0 + r) * NOUT_ + c4) = v;
        }
    }
}

extern "C" void kernel_launch(void* const* d_in, const int* in_sizes, int n_in,
                              void* d_out, int out_size, void* d_ws, size_t ws_size,
                              hipStream_t stream) {
    const float* x     = (const float*)d_in[0];
    const float* w_ih  = (const float*)d_in[1];
    const float* w_hh  = (const float*)d_in[2];
    const float* b_ih  = (const float*)d_in[3];
    const float* b_hh  = (const float*)d_in[4];
    const float* w_out = (const float*)d_in[5];
    const float* b_out = (const float*)d_in[6];

    _Float16* xp2   = (_Float16*)d_ws;                 // 67.1 MB [B][T/8][H][8]
    _Float16* hsbuf = xp2 + (size_t)TB_ * H_;          // 67.1 MB [T][B][H]

    k1_xproj<<<1024, 256, 0, stream>>>(x, w_ih, b_ih, b_hh, xp2);
    k2_scan <<<B_,   512, 0, stream>>>(xp2, w_hh, hsbuf);
    k3_out  <<<1024, 256, 0, stream>>>(hsbuf, w_out, b_out, (float*)d_out);
}

// Round 4
// 1056.473 us; speedup vs baseline: 1.0876x; 1.0876x over previous
//
#include <hip/hip_runtime.h>
#include <hip/hip_bf16.h>
#include <hip/hip_fp16.h>

#define T_ 2048
#define B_ 64
#define NIN_ 128
#define H_ 256
#define NOUT_ 128
#define TB_ (T_*B_)
#define BH_ (B_*H_)
#define TBLK2_ (T_/16)   // 128 blocks of 16 timesteps (fused-xproj granule)

typedef _Float16 h8 __attribute__((ext_vector_type(8)));
typedef _Float16 h4 __attribute__((ext_vector_type(4)));
typedef float f32x4 __attribute__((ext_vector_type(4)));

// LDS-only barrier: do NOT drain vmcnt (global loads/stores stay in flight).
#define BAR_LGKM() asm volatile("s_waitcnt lgkmcnt(0)\n\ts_barrier" ::: "memory")

__device__ __forceinline__ h8 cvt8(float4 a, float4 b) {
    h8 r;
    r[0] = (_Float16)a.x; r[1] = (_Float16)a.y; r[2] = (_Float16)a.z; r[3] = (_Float16)a.w;
    r[4] = (_Float16)b.x; r[5] = (_Float16)b.y; r[6] = (_Float16)b.z; r[7] = (_Float16)b.w;
    return r;
}
__device__ __forceinline__ h8 ld_cvt8(const float* __restrict__ p) {
    const float4* q = (const float4*)p;
    return cvt8(q[0], q[1]);
}

// ---------------------------------------------------------------------------
// K2: sequential scan with FUSED input projection (k1 eliminated).
//
// Core per-step structure identical to the proven 8-wave MFMA kernel
// (828 us): 512 thr, 2 N-tiles/wave, h double-buffered in LDS, 1 lgkm-only
// barrier/step, quads 2-3 duplicate quads 0-1.
//
// Fusion: per 16-step block, xp[t][j] = x[t]@W_ih^T + (b_ih+b_hh) is
// computed in-kernel: A = 16 x-rows (M-dim = timesteps, finally non-
// redundant), B = W_ih col-slice per wave -> 8 MFMA/wave per 16 steps
// (+~10 cyc/step pipe, issued during serial phases). Results transpose-
// written to LDS xpb[2][256][24] (k1's proven stride-24 layout), read back
// one h8/lane per 8 steps. x f32 fragments prefetched 2 blocks (32 steps)
// ahead; vmcnt never drained by the step barrier.
// ---------------------------------------------------------------------------
__global__ __launch_bounds__(512, 1) void k2_scan(
    const float* __restrict__ x,           // [T][B][NIN] f32
    const float* __restrict__ w_ih,        // [H][NIN] f32
    const float* __restrict__ w_hh,        // [H][H] f32
    const float* __restrict__ b_ih,
    const float* __restrict__ b_hh,
    _Float16* __restrict__ hs)             // [T][B][H] f16
{
    const int tid = threadIdx.x;
    const int lane = tid & 63, wave = tid >> 6;   // wave 0..7
    const int n = lane & 15, quad = lane >> 4;
    const int b = blockIdx.x;
    const int tsel = quad & 1;                    // which of the wave's 2 N-tiles
    const int j = wave*32 + tsel*16 + n;          // owned output column (reads)
    const bool writer = (quad < 2);               // quads 2,3 duplicate 0,1

    // W_hh B-frags: 2 tiles x 8 K-chunks (64 VGPRs)
    h8 bf[2][8];
    #pragma unroll
    for (int t = 0; t < 2; ++t)
        #pragma unroll
        for (int kt = 0; kt < 8; ++kt)
            bf[t][kt] = ld_cvt8(w_hh + (size_t)(wave*32 + t*16 + n) * H_ + kt*32 + quad*8);

    // W_ih B-frags: 2 tiles x 4 K-chunks (32 VGPRs)
    h8 bih[2][4];
    #pragma unroll
    for (int t = 0; t < 2; ++t)
        #pragma unroll
        for (int kt = 0; kt < 4; ++kt)
            bih[t][kt] = ld_cvt8(w_ih + (size_t)(wave*32 + t*16 + n) * NIN_ + kt*32 + quad*8);

    // xproj bias per tile (col = wave*32 + t*16 + n)
    float xbias[2];
    #pragma unroll
    for (int t = 0; t < 2; ++t) {
        int c = wave*32 + t*16 + n;
        xbias[t] = b_ih[c] + b_hh[c];
    }

    __shared__ __align__(16) _Float16 hb[2][256];
    __shared__ __align__(16) _Float16 xpb[2][256][24];   // [blk parity][j][t%16], stride 24

    // x fragment loader for 16-step block blk: lane (n,quad) reads
    // x[blk*16 + n][b][kt*32 + quad*8 .. +8] as 2 float4 per kt.
#define LOAD_X(blk)                                                            \
    {                                                                          \
        _Pragma("unroll")                                                      \
        for (int kt = 0; kt < 4; ++kt) {                                       \
            const float4* q = (const float4*)(x + ((size_t)((blk)*16 + n) * B_ + b) * NIN_ + kt*32 + quad*8); \
            xr[kt][0] = q[0]; xr[kt][1] = q[1];                                \
        }                                                                      \
    }

#define XPROJ_MFMA()                                                           \
    {                                                                          \
        xacc[0] = (f32x4){0,0,0,0}; xacc[1] = (f32x4){0,0,0,0};                \
        _Pragma("unroll")                                                      \
        for (int kt = 0; kt < 4; ++kt) {                                       \
            xacc[0] = __builtin_amdgcn_mfma_f32_16x16x32_f16(axv[kt], bih[0][kt], xacc[0], 0, 0, 0); \
            xacc[1] = __builtin_amdgcn_mfma_f32_16x16x32_f16(axv[kt], bih[1][kt], xacc[1], 0, 0, 0); \
        }                                                                      \
    }

    // write xacc -> xpb[buf]: lane holds rows t=quad*4+r of col c (per tile)
#define XPROJ_WRITE(buf)                                                       \
    {                                                                          \
        _Pragma("unroll")                                                      \
        for (int t = 0; t < 2; ++t) {                                          \
            int c = wave*32 + t*16 + n;                                        \
            h4 v;                                                              \
            _Pragma("unroll")                                                  \
            for (int r = 0; r < 4; ++r) v[r] = (_Float16)(xacc[t][r] + xbias[t]); \
            *(h4*)&xpb[buf][c][quad*4] = v;                                    \
        }                                                                      \
    }

    float4 xr[4][2];
    h8 axv[4];
    f32x4 xacc[2];

    // --- prologue: xproj for block 0, prefetch x for block 1 ---
    LOAD_X(0);
    #pragma unroll
    for (int kt = 0; kt < 4; ++kt) axv[kt] = cvt8(xr[kt][0], xr[kt][1]);
    XPROJ_MFMA();
    XPROJ_WRITE(0);
    LOAD_X(1);                              // consumed during block 0 (gen for block 1)
    if (tid < 256) hb[0][tid] = (_Float16)0.0f;
    __syncthreads();

    _Float16* hsl = hs + (size_t)b * H_ + j;

#define K2_STEP(T, RB, WB, XV)                                                 \
    {                                                                          \
        const h8* hp = (const h8*)&RB[0];                                      \
        h8 av[8];                                                              \
        _Pragma("unroll")                                                      \
        for (int kt = 0; kt < 8; ++kt) av[kt] = hp[kt*4 + quad];               \
        f32x4 acc[2];                                                          \
        acc[0] = (f32x4){0,0,0,0}; acc[1] = (f32x4){0,0,0,0};                  \
        _Pragma("unroll")                                                      \
        for (int kt = 0; kt < 8; ++kt) {                                       \
            acc[0] = __builtin_amdgcn_mfma_f32_16x16x32_f16(av[kt], bf[0][kt], acc[0], 0, 0, 0); \
            acc[1] = __builtin_amdgcn_mfma_f32_16x16x32_f16(av[kt], bf[1][kt], acc[1], 0, 0, 0); \
        }                                                                      \
        float vv = tsel ? acc[1][0] : acc[0][0];                               \
        float sv = vv + (XV);                                                  \
        float e  = __expf(2.0f * sv);                                          \
        float hn = fmaf(-2.0f, __builtin_amdgcn_rcpf(e + 1.0f), 1.0f);         \
        _Float16 h16 = (_Float16)hn;                                           \
        if (writer) {                                                          \
            WB[j] = h16;                                                       \
            hsl[(size_t)(T) * BH_] = h16;                                      \
        }                                                                      \
        BAR_LGKM();                                                            \
    }

    for (int tb = 0; tb < TBLK2_; ++tb) {
        const int p = tb & 1;
        const int t0 = tb * 16;
        const bool gen = (tb < TBLK2_ - 1);

        h8 cur0 = *(const h8*)&xpb[p][j][0];
        K2_STEP(t0 + 0, hb[0], hb[1], (float)cur0[0])
        if (gen) {                              // cvt x frags (VALU, hides under ds latency)
            #pragma unroll
            for (int kt = 0; kt < 4; ++kt) axv[kt] = cvt8(xr[kt][0], xr[kt][1]);
        }
        K2_STEP(t0 + 1, hb[1], hb[0], (float)cur0[1])
        if (gen) { XPROJ_MFMA(); }              // 8 MFMA into pipe slack
        K2_STEP(t0 + 2, hb[0], hb[1], (float)cur0[2])
        if (gen) { XPROJ_WRITE(p ^ 1); }        // xacc ready (~2 steps of latency)
        K2_STEP(t0 + 3, hb[1], hb[0], (float)cur0[3])
        if (tb < TBLK2_ - 2) { LOAD_X(tb + 2); }  // 2 blocks (32 steps) in flight
        K2_STEP(t0 + 4, hb[0], hb[1], (float)cur0[4])
        K2_STEP(t0 + 5, hb[1], hb[0], (float)cur0[5])
        K2_STEP(t0 + 6, hb[0], hb[1], (float)cur0[6])
        K2_STEP(t0 + 7, hb[1], hb[0], (float)cur0[7])
        h8 cur1 = *(const h8*)&xpb[p][j][8];
        K2_STEP(t0 + 8,  hb[0], hb[1], (float)cur1[0])
        K2_STEP(t0 + 9,  hb[1], hb[0], (float)cur1[1])
        K2_STEP(t0 + 10, hb[0], hb[1], (float)cur1[2])
        K2_STEP(t0 + 11, hb[1], hb[0], (float)cur1[3])
        K2_STEP(t0 + 12, hb[0], hb[1], (float)cur1[4])
        K2_STEP(t0 + 13, hb[1], hb[0], (float)cur1[5])
        K2_STEP(t0 + 14, hb[0], hb[1], (float)cur1[6])
        K2_STEP(t0 + 15, hb[1], hb[0], (float)cur1[7])
    }
#undef K2_STEP
#undef LOAD_X
#undef XPROJ_MFMA
#undef XPROJ_WRITE
}

// ---------------------------------------------------------------------------
// K3: out[TB][128](f32) = hs[TB][256](f16) @ W_out^T + b_out   (MFMA C^T)
// (unchanged from proven baseline)
// ---------------------------------------------------------------------------
__global__ __launch_bounds__(256, 2) void k3_out(
    const _Float16* __restrict__ hs,
    const float* __restrict__ w_out,
    const float* __restrict__ b_out,
    float* __restrict__ out)
{
    const int tid = threadIdx.x;
    const int lane = tid & 63, wave = tid >> 6;
    const int m = lane & 15, quad = lane >> 4;

    h8 af[2][8];
    #pragma unroll
    for (int i = 0; i < 2; ++i)
        #pragma unroll
        for (int kt = 0; kt < 8; ++kt)
            af[i][kt] = ld_cvt8(w_out + (size_t)(wave*32 + i*16 + m) * H_ + kt*32 + quad*8);

    float bias[2][4];
    #pragma unroll
    for (int i = 0; i < 2; ++i)
        #pragma unroll
        for (int r = 0; r < 4; ++r)
            bias[i][r] = b_out[wave*32 + i*16 + quad*4 + r];

    __shared__ __align__(16) float st[2][16][132];

    h8 bf[8];
    {
        const size_t n0 = (size_t)blockIdx.x * 128;
        #pragma unroll
        for (int kt = 0; kt < 8; ++kt)
            bf[kt] = *(const h8*)(hs + (n0 + m) * H_ + kt*32 + quad*8);
    }

    for (int rt = 0; rt < 8; ++rt) {
        const size_t n0 = (size_t)blockIdx.x * 128 + rt * 16;

        h8 cur[8];
        #pragma unroll
        for (int kt = 0; kt < 8; ++kt) cur[kt] = bf[kt];

        if (rt < 7) {
            #pragma unroll
            for (int kt = 0; kt < 8; ++kt)
                bf[kt] = *(const h8*)(hs + (n0 + 16 + m) * H_ + kt*32 + quad*8);
        }

        f32x4 acc[2];
        #pragma unroll
        for (int i = 0; i < 2; ++i) acc[i] = (f32x4){0,0,0,0};
        #pragma unroll
        for (int i = 0; i < 2; ++i)
            #pragma unroll
            for (int kt = 0; kt < 8; ++kt)
                acc[i] = __builtin_amdgcn_mfma_f32_16x16x32_f16(af[i][kt], cur[kt], acc[i], 0, 0, 0);

        const int p = rt & 1;
        #pragma unroll
        for (int i = 0; i < 2; ++i) {
            f32x4 v;
            #pragma unroll
            for (int r = 0; r < 4; ++r) v[r] = acc[i][r] + bias[i][r];
            *(f32x4*)&st[p][m][wave*32 + i*16 + quad*4] = v;
        }
        BAR_LGKM();
        #pragma unroll
        for (int it = 0; it < 2; ++it) {
            int idx = tid + it*256;
            int r = idx >> 5, c4 = (idx & 31) * 4;
            f32x4 v = *(const f32x4*)&st[p][r][c4];
            *(f32x4*)(out + (n0 + r) * NOUT_ + c4) = v;
        }
    }
}

extern "C" void kernel_launch(void* const* d_in, const int* in_sizes, int n_in,
                              void* d_out, int out_size, void* d_ws, size_t ws_size,
                              hipStream_t stream) {
    const float* x     = (const float*)d_in[0];
    const float* w_ih  = (const float*)d_in[1];
    const float* w_hh  = (const float*)d_in[2];
    const float* b_ih  = (const float*)d_in[3];
    const float* b_hh  = (const float*)d_in[4];
    const float* w_out = (const float*)d_in[5];
    const float* b_out = (const float*)d_in[6];

    _Float16* hsbuf = (_Float16*)d_ws;                 // 67.1 MB [T][B][H] f16

    k2_scan<<<B_,   512, 0, stream>>>(x, w_ih, w_hh, b_ih, b_hh, hsbuf);
    k3_out <<<1024, 256, 0, stream>>>(hsbuf, w_out, b_out, (float*)d_out);
}

// Round 5
// 1055.725 us; speedup vs baseline: 1.0884x; 1.0007x over previous
//
#include <hip/hip_runtime.h>
#include <hip/hip_bf16.h>
#include <hip/hip_fp16.h>

#define T_ 2048
#define B_ 64
#define NIN_ 128
#define H_ 256
#define NOUT_ 128
#define TB_ (T_*B_)
#define BH_ (B_*H_)
#define TBLK2_ (T_/16)   // 128 blocks of 16 timesteps (fused-xproj granule)

typedef _Float16 h8 __attribute__((ext_vector_type(8)));
typedef _Float16 h4 __attribute__((ext_vector_type(4)));
typedef float f32x4 __attribute__((ext_vector_type(4)));

// LDS-only barrier: do NOT drain vmcnt (global loads/stores stay in flight).
#define BAR_LGKM() asm volatile("s_waitcnt lgkmcnt(0)\n\ts_barrier" ::: "memory")

__device__ __forceinline__ h8 cvt8(float4 a, float4 b) {
    h8 r;
    r[0] = (_Float16)a.x; r[1] = (_Float16)a.y; r[2] = (_Float16)a.z; r[3] = (_Float16)a.w;
    r[4] = (_Float16)b.x; r[5] = (_Float16)b.y; r[6] = (_Float16)b.z; r[7] = (_Float16)b.w;
    return r;
}
__device__ __forceinline__ h8 ld_cvt8(const float* __restrict__ p) {
    const float4* q = (const float4*)p;
    return cvt8(q[0], q[1]);
}

// ---------------------------------------------------------------------------
// K2: sequential scan with FUSED input projection (no k1).
//
// Core per-step structure identical to the proven 8-wave MFMA kernel:
// 512 thr, 2 N-tiles/wave, h double-buffered in LDS, 1 lgkm-only
// barrier/step, quads 2-3 duplicate quads 0-1.
//
// Fusion schedule (fix for round-4's +60us stall): the 8 xproj MFMAs are
// spread ONE K-chunk per step across steps 1..4 (two independent acc
// chains; dep distance = 1 full step ~900cyc >> MFMA latency), the
// dependent LDS write is at step 6 (2 steps after last MFMA), x prefetch
// at step 5. Each piece is pinned with sched_barrier(0) because hipcc
// sinks register-only MFMAs past asm memory clobbers (rule #18), which
// would re-bunch them at the write and recreate the chain stall.
// ---------------------------------------------------------------------------
__global__ __launch_bounds__(512, 1) void k2_scan(
    const float* __restrict__ x,           // [T][B][NIN] f32
    const float* __restrict__ w_ih,        // [H][NIN] f32
    const float* __restrict__ w_hh,        // [H][H] f32
    const float* __restrict__ b_ih,
    const float* __restrict__ b_hh,
    _Float16* __restrict__ hs)             // [T][B][H] f16
{
    const int tid = threadIdx.x;
    const int lane = tid & 63, wave = tid >> 6;   // wave 0..7
    const int n = lane & 15, quad = lane >> 4;
    const int b = blockIdx.x;
    const int tsel = quad & 1;                    // which of the wave's 2 N-tiles
    const int j = wave*32 + tsel*16 + n;          // owned output column (reads)
    const bool writer = (quad < 2);               // quads 2,3 duplicate 0,1

    // W_hh B-frags: 2 tiles x 8 K-chunks (64 VGPRs)
    h8 bf[2][8];
    #pragma unroll
    for (int t = 0; t < 2; ++t)
        #pragma unroll
        for (int kt = 0; kt < 8; ++kt)
            bf[t][kt] = ld_cvt8(w_hh + (size_t)(wave*32 + t*16 + n) * H_ + kt*32 + quad*8);

    // W_ih B-frags: 2 tiles x 4 K-chunks (32 VGPRs)
    h8 bih[2][4];
    #pragma unroll
    for (int t = 0; t < 2; ++t)
        #pragma unroll
        for (int kt = 0; kt < 4; ++kt)
            bih[t][kt] = ld_cvt8(w_ih + (size_t)(wave*32 + t*16 + n) * NIN_ + kt*32 + quad*8);

    // xproj bias per tile (col = wave*32 + t*16 + n)
    float xbias[2];
    #pragma unroll
    for (int t = 0; t < 2; ++t) {
        int c = wave*32 + t*16 + n;
        xbias[t] = b_ih[c] + b_hh[c];
    }

    __shared__ __align__(16) _Float16 hb[2][256];
    __shared__ __align__(16) _Float16 xpb[2][256][24];   // [blk parity][j][t%16], stride 24

#define LOAD_X(blk)                                                            \
    {                                                                          \
        _Pragma("unroll")                                                      \
        for (int kt = 0; kt < 4; ++kt) {                                       \
            const float4* q = (const float4*)(x + ((size_t)((blk)*16 + n) * B_ + b) * NIN_ + kt*32 + quad*8); \
            xr[kt][0] = q[0]; xr[kt][1] = q[1];                                \
        }                                                                      \
    }

    // one K-chunk of the xproj GEMM (two independent acc chains)
#define XPROJ_PIECE(kt)                                                        \
    {                                                                          \
        xacc[0] = __builtin_amdgcn_mfma_f32_16x16x32_f16(axv[kt], bih[0][kt], xacc[0], 0, 0, 0); \
        xacc[1] = __builtin_amdgcn_mfma_f32_16x16x32_f16(axv[kt], bih[1][kt], xacc[1], 0, 0, 0); \
    }

    // write xacc -> xpb[buf]: lane holds rows t=quad*4+r of col c (per tile)
#define XPROJ_WRITE(buf)                                                       \
    {                                                                          \
        _Pragma("unroll")                                                      \
        for (int t = 0; t < 2; ++t) {                                          \
            int c = wave*32 + t*16 + n;                                        \
            h4 v;                                                              \
            _Pragma("unroll")                                                  \
            for (int r = 0; r < 4; ++r) v[r] = (_Float16)(xacc[t][r] + xbias[t]); \
            *(h4*)&xpb[buf][c][quad*4] = v;                                    \
        }                                                                      \
    }

    float4 xr[4][2];
    h8 axv[4];
    f32x4 xacc[2];

    // --- prologue: xproj for block 0, prefetch x for block 1 ---
    LOAD_X(0);
    #pragma unroll
    for (int kt = 0; kt < 4; ++kt) axv[kt] = cvt8(xr[kt][0], xr[kt][1]);
    xacc[0] = (f32x4){0,0,0,0}; xacc[1] = (f32x4){0,0,0,0};
    #pragma unroll
    for (int kt = 0; kt < 4; ++kt) XPROJ_PIECE(kt);
    XPROJ_WRITE(0);
    LOAD_X(1);                              // consumed during block 0 (gen for block 1)
    if (tid < 256) hb[0][tid] = (_Float16)0.0f;
    __syncthreads();

    _Float16* hsl = hs + (size_t)b * H_ + j;

#define K2_STEP(T, RB, WB, XV)                                                 \
    {                                                                          \
        const h8* hp = (const h8*)&RB[0];                                      \
        h8 av[8];                                                              \
        _Pragma("unroll")                                                      \
        for (int kt = 0; kt < 8; ++kt) av[kt] = hp[kt*4 + quad];               \
        f32x4 acc[2];                                                          \
        acc[0] = (f32x4){0,0,0,0}; acc[1] = (f32x4){0,0,0,0};                  \
        _Pragma("unroll")                                                      \
        for (int kt = 0; kt < 8; ++kt) {                                       \
            acc[0] = __builtin_amdgcn_mfma_f32_16x16x32_f16(av[kt], bf[0][kt], acc[0], 0, 0, 0); \
            acc[1] = __builtin_amdgcn_mfma_f32_16x16x32_f16(av[kt], bf[1][kt], acc[1], 0, 0, 0); \
        }                                                                      \
        float vv = tsel ? acc[1][0] : acc[0][0];                               \
        float sv = vv + (XV);                                                  \
        float e  = __expf(2.0f * sv);                                          \
        float hn = fmaf(-2.0f, __builtin_amdgcn_rcpf(e + 1.0f), 1.0f);         \
        _Float16 h16 = (_Float16)hn;                                           \
        if (writer) {                                                          \
            WB[j] = h16;                                                       \
            hsl[(size_t)(T) * BH_] = h16;                                      \
        }                                                                      \
        BAR_LGKM();                                                            \
    }

    for (int tb = 0; tb < TBLK2_; ++tb) {
        const int p = tb & 1;
        const int t0 = tb * 16;
        const bool gen = (tb < TBLK2_ - 1);

        h8 cur0 = *(const h8*)&xpb[p][j][0];
        K2_STEP(t0 + 0, hb[0], hb[1], (float)cur0[0])
        if (gen) {                              // cvt x frags; zero xproj accs
            #pragma unroll
            for (int kt = 0; kt < 4; ++kt) axv[kt] = cvt8(xr[kt][0], xr[kt][1]);
            xacc[0] = (f32x4){0,0,0,0}; xacc[1] = (f32x4){0,0,0,0};
            __builtin_amdgcn_sched_barrier(0);
        }
        K2_STEP(t0 + 1, hb[1], hb[0], (float)cur0[1])
        if (gen) { XPROJ_PIECE(0); __builtin_amdgcn_sched_barrier(0); }
        K2_STEP(t0 + 2, hb[0], hb[1], (float)cur0[2])
        if (gen) { XPROJ_PIECE(1); __builtin_amdgcn_sched_barrier(0); }
        K2_STEP(t0 + 3, hb[1], hb[0], (float)cur0[3])
        if (gen) { XPROJ_PIECE(2); __builtin_amdgcn_sched_barrier(0); }
        K2_STEP(t0 + 4, hb[0], hb[1], (float)cur0[4])
        if (gen) { XPROJ_PIECE(3); __builtin_amdgcn_sched_barrier(0); }
        K2_STEP(t0 + 5, hb[1], hb[0], (float)cur0[5])
        if (tb < TBLK2_ - 2) { LOAD_X(tb + 2); }  // 2 blocks (32 steps) in flight
        K2_STEP(t0 + 6, hb[0], hb[1], (float)cur0[6])
        if (gen) { XPROJ_WRITE(p ^ 1); }        // xacc final for ~2 steps already
        K2_STEP(t0 + 7, hb[1], hb[0], (float)cur0[7])
        h8 cur1 = *(const h8*)&xpb[p][j][8];
        K2_STEP(t0 + 8,  hb[0], hb[1], (float)cur1[0])
        K2_STEP(t0 + 9,  hb[1], hb[0], (float)cur1[1])
        K2_STEP(t0 + 10, hb[0], hb[1], (float)cur1[2])
        K2_STEP(t0 + 11, hb[1], hb[0], (float)cur1[3])
        K2_STEP(t0 + 12, hb[0], hb[1], (float)cur1[4])
        K2_STEP(t0 + 13, hb[1], hb[0], (float)cur1[5])
        K2_STEP(t0 + 14, hb[0], hb[1], (float)cur1[6])
        K2_STEP(t0 + 15, hb[1], hb[0], (float)cur1[7])
    }
#undef K2_STEP
#undef LOAD_X
#undef XPROJ_PIECE
#undef XPROJ_WRITE
}

// ---------------------------------------------------------------------------
// K3: out[TB][128](f32) = hs[TB][256](f16) @ W_out^T + b_out
// Rewritten: wave-private 16-row tiles (old version's 4 waves loaded the
// SAME 16 rows -> 4x redundant hs fetch). Each wave holds W_out for ALL
// 128 cols (af[8][8], 128 VGPR, loaded once, reused over 8 row-iters).
// Grid 256 WGs x 512 rows. Epilogue through wave-private LDS tile
// (conflict-free both directions) -> no s_barrier anywhere.
// ---------------------------------------------------------------------------
__global__ __launch_bounds__(256, 1) void k3_out(
    const _Float16* __restrict__ hs,
    const float* __restrict__ w_out,
    const float* __restrict__ b_out,
    float* __restrict__ out)
{
    const int tid = threadIdx.x;
    const int lane = tid & 63, wave = tid >> 6;
    const int m = lane & 15, quad = lane >> 4;

    // all 128 output cols x 8 K-chunks (128 VGPRs)
    h8 af[8][8];
    #pragma unroll
    for (int i = 0; i < 8; ++i)
        #pragma unroll
        for (int kt = 0; kt < 8; ++kt)
            af[i][kt] = ld_cvt8(w_out + (size_t)(i*16 + m) * H_ + kt*32 + quad*8);

    __shared__ __align__(16) float st[4][16][132];   // per-wave private tile

    const size_t base = (size_t)blockIdx.x * 512 + (size_t)wave * 16;

    h8 nxt[8];
    #pragma unroll
    for (int kt = 0; kt < 8; ++kt)
        nxt[kt] = *(const h8*)(hs + (base + m) * H_ + kt*32 + quad*8);

    for (int it = 0; it < 8; ++it) {
        const size_t n0 = base + (size_t)it * 64;

        h8 cur[8];
        #pragma unroll
        for (int kt = 0; kt < 8; ++kt) cur[kt] = nxt[kt];

        if (it < 7) {
            #pragma unroll
            for (int kt = 0; kt < 8; ++kt)
                nxt[kt] = *(const h8*)(hs + (n0 + 64 + m) * H_ + kt*32 + quad*8);
        }

        f32x4 acc[8];
        #pragma unroll
        for (int i = 0; i < 8; ++i) acc[i] = (f32x4){0,0,0,0};
        #pragma unroll
        for (int kt = 0; kt < 8; ++kt)
            #pragma unroll
            for (int i = 0; i < 8; ++i)
                acc[i] = __builtin_amdgcn_mfma_f32_16x16x32_f16(af[i][kt], cur[kt], acc[i], 0, 0, 0);

        // acc[i][r] = value for hs-row m, out-col i*16+quad*4+r
        #pragma unroll
        for (int i = 0; i < 8; ++i)
            *(f32x4*)&st[wave][m][i*16 + quad*4] = acc[i];
        asm volatile("s_waitcnt lgkmcnt(0)" ::: "memory");   // wave-private: no barrier

        #pragma unroll
        for (int c = 0; c < 8; ++c) {
            int idx = lane + c*64;               // 0..511
            int r = idx >> 5, c4 = (idx & 31) * 4;
            f32x4 v = *(const f32x4*)&st[wave][r][c4];
            f32x4 bb = *(const f32x4*)(b_out + c4);
            v[0] += bb[0]; v[1] += bb[1]; v[2] += bb[2]; v[3] += bb[3];
            *(f32x4*)(out + (n0 + r) * NOUT_ + c4) = v;
        }
    }
}

extern "C" void kernel_launch(void* const* d_in, const int* in_sizes, int n_in,
                              void* d_out, int out_size, void* d_ws, size_t ws_size,
                              hipStream_t stream) {
    const float* x     = (const float*)d_in[0];
    const float* w_ih  = (const float*)d_in[1];
    const float* w_hh  = (const float*)d_in[2];
    const float* b_ih  = (const float*)d_in[3];
    const float* b_hh  = (const float*)d_in[4];
    const float* w_out = (const float*)d_in[5];
    const float* b_out = (const float*)d_in[6];

    _Float16* hsbuf = (_Float16*)d_ws;                 // 67.1 MB [T][B][H] f16

    k2_scan<<<B_,  512, 0, stream>>>(x, w_ih, w_hh, b_ih, b_hh, hsbuf);
    k3_out <<<256, 256, 0, stream>>>(hsbuf, w_out, b_out, (float*)d_out);
}

// Round 7
// 859.969 us; speedup vs baseline: 1.3362x; 1.2276x over previous
//
#include <hip/hip_runtime.h>
#include <hip/hip_bf16.h>
#include <hip/hip_fp16.h>

#define T_ 2048
#define B_ 64
#define NIN_ 128
#define H_ 256
#define NOUT_ 128
#define TB_ (T_*B_)
#define BH_ (B_*H_)
#define TBLK2_ (T_/16)   // 128 blocks of 16 timesteps

typedef _Float16 h8 __attribute__((ext_vector_type(8)));
typedef float f32x4 __attribute__((ext_vector_type(4)));

// LDS-only barrier: do NOT drain vmcnt (global loads/stores stay in flight).
#define BAR_LGKM() asm volatile("s_waitcnt lgkmcnt(0)\n\ts_barrier" ::: "memory")

__device__ __forceinline__ h8 cvt8(float4 a, float4 b) {
    h8 r;
    r[0] = (_Float16)a.x; r[1] = (_Float16)a.y; r[2] = (_Float16)a.z; r[3] = (_Float16)a.w;
    r[4] = (_Float16)b.x; r[5] = (_Float16)b.y; r[6] = (_Float16)b.z; r[7] = (_Float16)b.w;
    return r;
}
__device__ __forceinline__ h8 ld_cvt8(const float* __restrict__ p) {
    const float4* q = (const float4*)p;
    return cvt8(q[0], q[1]);
}

// ---------------------------------------------------------------------------
// K2: sequential scan + fused input projection, WAVE-SPECIALIZED.
//
// 768 threads = 12 waves (3/SIMD):
//   waves 0-7  (scan): byte-identical round-2 loop (828us proven shape) —
//     2 N-tiles/wave, h double-buffered in LDS, 16 MFMA/step, 1 lgkm-only
//     barrier/step. XV comes from LDS xpb instead of global. No extra live
//     registers in the loop -> compiler keeps the front-loaded ds_read
//     schedule (round-4/5's +120cyc/step was fused-path register pressure
//     serializing the av reads; producers now own that state).
//   waves 8-11 (xproj): each owns 64 output cols; k1's proven tile —
//     MFMA(A = W_ih rows, B = 16 x-timesteps) — EXACT k1 operand order
//     (round-6 failed because A/B were swapped, transposing the C frag).
//     Work spread over the same 16-barrier/block ladder: cvt@1, one
//     K-chunk MFMA @2..5, transpose-write@7, x-prefetch(+2 blocks)@8.
// Both paths execute EXACTLY 1 prologue barrier + 16 barriers per block.
// ---------------------------------------------------------------------------
__global__ __launch_bounds__(768, 1) void k2_scan(
    const float* __restrict__ x,           // [T][B][NIN] f32
    const float* __restrict__ w_ih,        // [H][NIN] f32
    const float* __restrict__ w_hh,        // [H][H] f32
    const float* __restrict__ b_ih,
    const float* __restrict__ b_hh,
    _Float16* __restrict__ hs)             // [T][B][H] f16
{
    const int tid = threadIdx.x;
    const int lane = tid & 63, wave = tid >> 6;   // 0..11
    const int n = lane & 15, quad = lane >> 4;
    const int b = blockIdx.x;

    __shared__ __align__(16) _Float16 hb[2][256];
    __shared__ __align__(16) _Float16 xpb[2][256][24];   // [parity][col][t%16], stride 24

    if (wave < 8) {
        // ================= scan waves =================
        const int tsel = quad & 1;
        const int j = wave*32 + tsel*16 + n;      // owned output column
        const bool writer = (quad < 2);           // quads 2,3 duplicate 0,1

        h8 bf[2][8];
        #pragma unroll
        for (int t = 0; t < 2; ++t)
            #pragma unroll
            for (int kt = 0; kt < 8; ++kt)
                bf[t][kt] = ld_cvt8(w_hh + (size_t)(wave*32 + t*16 + n) * H_ + kt*32 + quad*8);

        if (tid < 256) hb[0][tid] = (_Float16)0.0f;
        asm volatile("s_waitcnt lgkmcnt(0) vmcnt(0)" ::: "memory");
        __builtin_amdgcn_s_barrier();

        _Float16* hsl = hs + (size_t)b * H_ + j;

#define K2_STEP(T, RB, WB, XV)                                                 \
    {                                                                          \
        const h8* hp = (const h8*)&RB[0];                                      \
        h8 av[8];                                                              \
        _Pragma("unroll")                                                      \
        for (int kt = 0; kt < 8; ++kt) av[kt] = hp[kt*4 + quad];               \
        f32x4 acc[2];                                                          \
        acc[0] = (f32x4){0,0,0,0}; acc[1] = (f32x4){0,0,0,0};                  \
        __builtin_amdgcn_s_setprio(1);                                         \
        _Pragma("unroll")                                                      \
        for (int kt = 0; kt < 8; ++kt) {                                       \
            acc[0] = __builtin_amdgcn_mfma_f32_16x16x32_f16(av[kt], bf[0][kt], acc[0], 0, 0, 0); \
            acc[1] = __builtin_amdgcn_mfma_f32_16x16x32_f16(av[kt], bf[1][kt], acc[1], 0, 0, 0); \
        }                                                                      \
        __builtin_amdgcn_s_setprio(0);                                         \
        float vv = tsel ? acc[1][0] : acc[0][0];                               \
        float sv = vv + (XV);                                                  \
        float e  = __expf(2.0f * sv);                                          \
        float hn = fmaf(-2.0f, __builtin_amdgcn_rcpf(e + 1.0f), 1.0f);         \
        _Float16 h16 = (_Float16)hn;                                           \
        if (writer) {                                                          \
            WB[j] = h16;                                                       \
            hsl[(size_t)(T) * BH_] = h16;                                      \
        }                                                                      \
        BAR_LGKM();                                                            \
    }

        for (int tb = 0; tb < TBLK2_; ++tb) {
            const int p = tb & 1;
            const int t0 = tb * 16;
            h8 cur0 = *(const h8*)&xpb[p][j][0];
            K2_STEP(t0 + 0, hb[0], hb[1], (float)cur0[0])
            K2_STEP(t0 + 1, hb[1], hb[0], (float)cur0[1])
            K2_STEP(t0 + 2, hb[0], hb[1], (float)cur0[2])
            K2_STEP(t0 + 3, hb[1], hb[0], (float)cur0[3])
            K2_STEP(t0 + 4, hb[0], hb[1], (float)cur0[4])
            K2_STEP(t0 + 5, hb[1], hb[0], (float)cur0[5])
            K2_STEP(t0 + 6, hb[0], hb[1], (float)cur0[6])
            K2_STEP(t0 + 7, hb[1], hb[0], (float)cur0[7])
            h8 cur1 = *(const h8*)&xpb[p][j][8];
            K2_STEP(t0 + 8,  hb[0], hb[1], (float)cur1[0])
            K2_STEP(t0 + 9,  hb[1], hb[0], (float)cur1[1])
            K2_STEP(t0 + 10, hb[0], hb[1], (float)cur1[2])
            K2_STEP(t0 + 11, hb[1], hb[0], (float)cur1[3])
            K2_STEP(t0 + 12, hb[0], hb[1], (float)cur1[4])
            K2_STEP(t0 + 13, hb[1], hb[0], (float)cur1[5])
            K2_STEP(t0 + 14, hb[0], hb[1], (float)cur1[6])
            K2_STEP(t0 + 15, hb[1], hb[0], (float)cur1[7])
        }
#undef K2_STEP
    } else {
        // ================= xproj producer waves =================
        const int w = wave - 8;                   // 0..3, owns cols [w*64, w*64+64)
        const int m = n;                          // timestep index within block

        // A-frags: W_ih rows (= xproj output cols), k1's proven layout
        h8 aih[4][4];
        #pragma unroll
        for (int i = 0; i < 4; ++i)
            #pragma unroll
            for (int kt = 0; kt < 4; ++kt)
                aih[i][kt] = ld_cvt8(w_ih + (size_t)(w*64 + i*16 + m) * NIN_ + kt*32 + quad*8);

        float xb2[4][4];
        #pragma unroll
        for (int i = 0; i < 4; ++i)
            #pragma unroll
            for (int r = 0; r < 4; ++r) {
                int c = w*64 + i*16 + quad*4 + r;
                xb2[i][r] = b_ih[c] + b_hh[c];
            }

        float4 xr[4][2];
        h8 bx[4];
        f32x4 xacc[4];

#define LOAD_X(blk)                                                            \
    {                                                                          \
        _Pragma("unroll")                                                      \
        for (int kt = 0; kt < 4; ++kt) {                                       \
            const float4* q = (const float4*)(x + ((size_t)((blk)*16 + m) * B_ + b) * NIN_ + kt*32 + quad*8); \
            xr[kt][0] = q[0]; xr[kt][1] = q[1];                                \
        }                                                                      \
    }

        // one K-chunk of xproj, k1's EXACT operand order: A=aih, B=bx
#define XPROJ_PIECE(kt)                                                        \
    {                                                                          \
        _Pragma("unroll")                                                      \
        for (int i = 0; i < 4; ++i)                                            \
            xacc[i] = __builtin_amdgcn_mfma_f32_16x16x32_f16(aih[i][kt], bx[kt], xacc[i], 0, 0, 0); \
    }

        // write xacc -> xpb[buf]: value for col c, timestep m (k1's epilogue)
#define XPROJ_WRITE(buf)                                                       \
    {                                                                          \
        _Pragma("unroll")                                                      \
        for (int i = 0; i < 4; ++i)                                            \
            _Pragma("unroll")                                                  \
            for (int r = 0; r < 4; ++r) {                                      \
                int c = w*64 + i*16 + quad*4 + r;                              \
                xpb[buf][c][m] = (_Float16)(xacc[i][r] + xb2[i][r]);           \
            }                                                                  \
    }

        // prologue: produce xpb[0] (block 0), prefetch x for block 1
        LOAD_X(0);
        #pragma unroll
        for (int kt = 0; kt < 4; ++kt) bx[kt] = cvt8(xr[kt][0], xr[kt][1]);
        #pragma unroll
        for (int i = 0; i < 4; ++i) xacc[i] = (f32x4){0,0,0,0};
        #pragma unroll
        for (int kt = 0; kt < 4; ++kt) XPROJ_PIECE(kt)
        XPROJ_WRITE(0);
        LOAD_X(1);
        asm volatile("s_waitcnt lgkmcnt(0) vmcnt(0)" ::: "memory");
        __builtin_amdgcn_s_barrier();

        for (int tb = 0; tb < TBLK2_; ++tb) {
            const int p = tb & 1;
            const bool gen = (tb < TBLK2_ - 1);
            // slot 1: cvt x frags (for block tb+1), zero accs
            if (gen) {
                #pragma unroll
                for (int kt = 0; kt < 4; ++kt) bx[kt] = cvt8(xr[kt][0], xr[kt][1]);
                #pragma unroll
                for (int i = 0; i < 4; ++i) xacc[i] = (f32x4){0,0,0,0};
            }
            __builtin_amdgcn_sched_barrier(0);
            BAR_LGKM();                                               // 1
            // slots 2..5: one K-chunk each (4 independent i-chains)
            if (gen) { XPROJ_PIECE(0) }
            __builtin_amdgcn_sched_barrier(0);
            BAR_LGKM();                                               // 2
            if (gen) { XPROJ_PIECE(1) }
            __builtin_amdgcn_sched_barrier(0);
            BAR_LGKM();                                               // 3
            if (gen) { XPROJ_PIECE(2) }
            __builtin_amdgcn_sched_barrier(0);
            BAR_LGKM();                                               // 4
            if (gen) { XPROJ_PIECE(3) }
            __builtin_amdgcn_sched_barrier(0);
            BAR_LGKM();                                               // 5
            BAR_LGKM();                                               // 6
            // slot 7: transpose-write next block's xproj into xpb
            if (gen) { XPROJ_WRITE(p ^ 1); }
            BAR_LGKM();                                               // 7
            // slot 8: prefetch x two blocks ahead
            if (tb < TBLK2_ - 2) { LOAD_X(tb + 2); }
            BAR_LGKM();                                               // 8
            BAR_LGKM();                                               // 9
            BAR_LGKM();                                               // 10
            BAR_LGKM();                                               // 11
            BAR_LGKM();                                               // 12
            BAR_LGKM();                                               // 13
            BAR_LGKM();                                               // 14
            BAR_LGKM();                                               // 15
            BAR_LGKM();                                               // 16
        }
#undef LOAD_X
#undef XPROJ_PIECE
#undef XPROJ_WRITE
    }
}

// ---------------------------------------------------------------------------
// K3: out[TB][128](f32) = hs[TB][256](f16) @ W_out^T + b_out
// Wave-private 16-row tiles; W_out held for all 128 cols (af[8][8], loaded
// once, reused over 8 row-iters). Grid 256 WGs x 512 rows. Epilogue through
// wave-private LDS tile -> no s_barrier anywhere.
// ---------------------------------------------------------------------------
__global__ __launch_bounds__(256, 1) void k3_out(
    const _Float16* __restrict__ hs,
    const float* __restrict__ w_out,
    const float* __restrict__ b_out,
    float* __restrict__ out)
{
    const int tid = threadIdx.x;
    const int lane = tid & 63, wave = tid >> 6;
    const int m = lane & 15, quad = lane >> 4;

    h8 af[8][8];
    #pragma unroll
    for (int i = 0; i < 8; ++i)
        #pragma unroll
        for (int kt = 0; kt < 8; ++kt)
            af[i][kt] = ld_cvt8(w_out + (size_t)(i*16 + m) * H_ + kt*32 + quad*8);

    __shared__ __align__(16) float st[4][16][132];   // per-wave private tile

    const size_t base = (size_t)blockIdx.x * 512 + (size_t)wave * 16;

    h8 nxt[8];
    #pragma unroll
    for (int kt = 0; kt < 8; ++kt)
        nxt[kt] = *(const h8*)(hs + (base + m) * H_ + kt*32 + quad*8);

    for (int it = 0; it < 8; ++it) {
        const size_t n0 = base + (size_t)it * 64;

        h8 cur[8];
        #pragma unroll
        for (int kt = 0; kt < 8; ++kt) cur[kt] = nxt[kt];

        if (it < 7) {
            #pragma unroll
            for (int kt = 0; kt < 8; ++kt)
                nxt[kt] = *(const h8*)(hs + (n0 + 64 + m) * H_ + kt*32 + quad*8);
        }

        f32x4 acc[8];
        #pragma unroll
        for (int i = 0; i < 8; ++i) acc[i] = (f32x4){0,0,0,0};
        #pragma unroll
        for (int kt = 0; kt < 8; ++kt)
            #pragma unroll
            for (int i = 0; i < 8; ++i)
                acc[i] = __builtin_amdgcn_mfma_f32_16x16x32_f16(af[i][kt], cur[kt], acc[i], 0, 0, 0);

        #pragma unroll
        for (int i = 0; i < 8; ++i)
            *(f32x4*)&st[wave][m][i*16 + quad*4] = acc[i];
        asm volatile("s_waitcnt lgkmcnt(0)" ::: "memory");   // wave-private: no barrier

        #pragma unroll
        for (int c = 0; c < 8; ++c) {
            int idx = lane + c*64;
            int r = idx >> 5, c4 = (idx & 31) * 4;
            f32x4 v = *(const f32x4*)&st[wave][r][c4];
            f32x4 bb = *(const f32x4*)(b_out + c4);
            v[0] += bb[0]; v[1] += bb[1]; v[2] += bb[2]; v[3] += bb[3];
            *(f32x4*)(out + (n0 + r) * NOUT_ + c4) = v;
        }
    }
}

extern "C" void kernel_launch(void* const* d_in, const int* in_sizes, int n_in,
                              void* d_out, int out_size, void* d_ws, size_t ws_size,
                              hipStream_t stream) {
    const float* x     = (const float*)d_in[0];
    const float* w_ih  = (const float*)d_in[1];
    const float* w_hh  = (const float*)d_in[2];
    const float* b_ih  = (const float*)d_in[3];
    const float* b_hh  = (const float*)d_in[4];
    const float* w_out = (const float*)d_in[5];
    const float* b_out = (const float*)d_in[6];

    _Float16* hsbuf = (_Float16*)d_ws;                 // 67.1 MB [T][B][H] f16

    k2_scan<<<B_,  768, 0, stream>>>(x, w_ih, w_hh, b_ih, b_hh, hsbuf);
    k3_out <<<256, 256, 0, stream>>>(hsbuf, w_out, b_out, (float*)d_out);
}

// Round 8
// 844.106 us; speedup vs baseline: 1.3613x; 1.0188x over previous
//
#include <hip/hip_runtime.h>
#include <hip/hip_bf16.h>
#include <hip/hip_fp16.h>

#define T_ 2048
#define B_ 64
#define NIN_ 128
#define H_ 256
#define NOUT_ 128
#define TB_ (T_*B_)
#define BH_ (B_*H_)
#define TBLK2_ (T_/16)   // 128 blocks of 16 timesteps

typedef _Float16 h8 __attribute__((ext_vector_type(8)));
typedef float f32x4 __attribute__((ext_vector_type(4)));

// LDS-only barrier: do NOT drain vmcnt (global loads/stores stay in flight).
#define BAR_LGKM() asm volatile("s_waitcnt lgkmcnt(0)\n\ts_barrier" ::: "memory")

__device__ __forceinline__ h8 cvt8(float4 a, float4 b) {
    h8 r;
    r[0] = (_Float16)a.x; r[1] = (_Float16)a.y; r[2] = (_Float16)a.z; r[3] = (_Float16)a.w;
    r[4] = (_Float16)b.x; r[5] = (_Float16)b.y; r[6] = (_Float16)b.z; r[7] = (_Float16)b.w;
    return r;
}
__device__ __forceinline__ h8 ld_cvt8(const float* __restrict__ p) {
    const float4* q = (const float4*)p;
    return cvt8(q[0], q[1]);
}

// ---------------------------------------------------------------------------
// FULLY FUSED RNN: one kernel, one WG per batch, 1024 threads = 16 waves
// (4/SIMD: 2 scan + 1 xproj-producer + 1 out-projection consumer).
//
//   waves 0-7  (scan): proven round-7 loop. h -> hb (double-buffered) AND
//     hist LDS ring (replaces the global hs store; scan loop now has ZERO
//     global ops). 16 MFMA/step, 1 lgkm-only barrier/step.
//   waves 8-11 (xproj producers): unchanged from round 7 — k1 tile
//     (A=W_ih rows, B=16 x-timesteps), transpose-write to xpb, x
//     prefetched 2 blocks ahead.
//   waves 12-15 (out-projection consumers): one block BEHIND the scan,
//     read 16 h-rows from hist as MFMA A-frags (M-dim = 16 timesteps ->
//     16x less MFMA than per-step matvec), B = W_out cols (static, 64
//     VGPR), C = out[t][b][o] written straight to global f32 (64B
//     contiguous per quad-row). 16 MFMA + 8 ds_read + 8 stores per block
//     per wave = ~1 MFMA/step -> rides in barrier-ladder slack.
//     Final block handled in a barrier-free epilogue.
//
// Every role executes exactly 1 prologue barrier + 16 barriers per block.
// Per-SIMD MFMA/step: 32 (scan) + ~1 (xproj) + ~1 (out) ~= 660 cyc, under
// the ~860-cyc measured step -> added work hides in pipe slack.
// ---------------------------------------------------------------------------
__global__ __launch_bounds__(1024, 1) void k2_fused(
    const float* __restrict__ x,           // [T][B][NIN] f32
    const float* __restrict__ w_ih,        // [H][NIN] f32
    const float* __restrict__ w_hh,        // [H][H] f32
    const float* __restrict__ b_ih,
    const float* __restrict__ b_hh,
    const float* __restrict__ w_out,       // [NOUT][H] f32
    const float* __restrict__ b_out,
    float* __restrict__ out)               // [T][B][NOUT] f32
{
    const int tid = threadIdx.x;
    const int lane = tid & 63, wave = tid >> 6;   // 0..15
    const int n = lane & 15, quad = lane >> 4;
    const int b = blockIdx.x;

    __shared__ __align__(16) _Float16 hb[2][256];
    __shared__ __align__(16) _Float16 xpb[2][256][24];   // [parity][col][t%16], stride 24
    __shared__ __align__(16) _Float16 hist[2][16][264];  // [parity][t%16][col], pad 264

    if (wave < 8) {
        // ================= scan waves =================
        const int tsel = quad & 1;
        const int j = wave*32 + tsel*16 + n;      // owned output column
        const bool writer = (quad < 2);           // quads 2,3 duplicate 0,1

        h8 bf[2][8];
        #pragma unroll
        for (int t = 0; t < 2; ++t)
            #pragma unroll
            for (int kt = 0; kt < 8; ++kt)
                bf[t][kt] = ld_cvt8(w_hh + (size_t)(wave*32 + t*16 + n) * H_ + kt*32 + quad*8);

        if (tid < 256) hb[0][tid] = (_Float16)0.0f;
        asm volatile("s_waitcnt lgkmcnt(0) vmcnt(0)" ::: "memory");
        __builtin_amdgcn_s_barrier();

#define K2_STEP(C, RB, WB, XV)                                                 \
    {                                                                          \
        const h8* hp = (const h8*)&RB[0];                                      \
        h8 av[8];                                                              \
        _Pragma("unroll")                                                      \
        for (int kt = 0; kt < 8; ++kt) av[kt] = hp[kt*4 + quad];               \
        f32x4 acc[2];                                                          \
        acc[0] = (f32x4){0,0,0,0}; acc[1] = (f32x4){0,0,0,0};                  \
        __builtin_amdgcn_s_setprio(1);                                         \
        _Pragma("unroll")                                                      \
        for (int kt = 0; kt < 8; ++kt) {                                       \
            acc[0] = __builtin_amdgcn_mfma_f32_16x16x32_f16(av[kt], bf[0][kt], acc[0], 0, 0, 0); \
            acc[1] = __builtin_amdgcn_mfma_f32_16x16x32_f16(av[kt], bf[1][kt], acc[1], 0, 0, 0); \
        }                                                                      \
        __builtin_amdgcn_s_setprio(0);                                         \
        float vv = tsel ? acc[1][0] : acc[0][0];                               \
        float sv = vv + (XV);                                                  \
        float e  = __expf(2.0f * sv);                                          \
        float hn = fmaf(-2.0f, __builtin_amdgcn_rcpf(e + 1.0f), 1.0f);         \
        _Float16 h16 = (_Float16)hn;                                           \
        if (writer) {                                                          \
            WB[j] = h16;                                                       \
            hist[p][C][j] = h16;                                               \
        }                                                                      \
        BAR_LGKM();                                                            \
    }

        for (int tb = 0; tb < TBLK2_; ++tb) {
            const int p = tb & 1;
            h8 cur0 = *(const h8*)&xpb[p][j][0];
            K2_STEP(0,  hb[0], hb[1], (float)cur0[0])
            K2_STEP(1,  hb[1], hb[0], (float)cur0[1])
            K2_STEP(2,  hb[0], hb[1], (float)cur0[2])
            K2_STEP(3,  hb[1], hb[0], (float)cur0[3])
            K2_STEP(4,  hb[0], hb[1], (float)cur0[4])
            K2_STEP(5,  hb[1], hb[0], (float)cur0[5])
            K2_STEP(6,  hb[0], hb[1], (float)cur0[6])
            K2_STEP(7,  hb[1], hb[0], (float)cur0[7])
            h8 cur1 = *(const h8*)&xpb[p][j][8];
            K2_STEP(8,  hb[0], hb[1], (float)cur1[0])
            K2_STEP(9,  hb[1], hb[0], (float)cur1[1])
            K2_STEP(10, hb[0], hb[1], (float)cur1[2])
            K2_STEP(11, hb[1], hb[0], (float)cur1[3])
            K2_STEP(12, hb[0], hb[1], (float)cur1[4])
            K2_STEP(13, hb[1], hb[0], (float)cur1[5])
            K2_STEP(14, hb[0], hb[1], (float)cur1[6])
            K2_STEP(15, hb[1], hb[0], (float)cur1[7])
        }
#undef K2_STEP
    } else if (wave < 12) {
        // ================= xproj producer waves =================
        const int w = wave - 8;                   // 0..3, owns cols [w*64, w*64+64)
        const int m = n;                          // timestep index within block

        h8 aih[4][4];
        #pragma unroll
        for (int i = 0; i < 4; ++i)
            #pragma unroll
            for (int kt = 0; kt < 4; ++kt)
                aih[i][kt] = ld_cvt8(w_ih + (size_t)(w*64 + i*16 + m) * NIN_ + kt*32 + quad*8);

        float xb2[4][4];
        #pragma unroll
        for (int i = 0; i < 4; ++i)
            #pragma unroll
            for (int r = 0; r < 4; ++r) {
                int c = w*64 + i*16 + quad*4 + r;
                xb2[i][r] = b_ih[c] + b_hh[c];
            }

        float4 xr[4][2];
        h8 bx[4];
        f32x4 xacc[4];

#define LOAD_X(blk)                                                            \
    {                                                                          \
        _Pragma("unroll")                                                      \
        for (int kt = 0; kt < 4; ++kt) {                                       \
            const float4* q = (const float4*)(x + ((size_t)((blk)*16 + m) * B_ + b) * NIN_ + kt*32 + quad*8); \
            xr[kt][0] = q[0]; xr[kt][1] = q[1];                                \
        }                                                                      \
    }

#define XPROJ_PIECE(kt)                                                        \
    {                                                                          \
        _Pragma("unroll")                                                      \
        for (int i = 0; i < 4; ++i)                                            \
            xacc[i] = __builtin_amdgcn_mfma_f32_16x16x32_f16(aih[i][kt], bx[kt], xacc[i], 0, 0, 0); \
    }

#define XPROJ_WRITE(buf)                                                       \
    {                                                                          \
        _Pragma("unroll")                                                      \
        for (int i = 0; i < 4; ++i)                                            \
            _Pragma("unroll")                                                  \
            for (int r = 0; r < 4; ++r) {                                      \
                int c = w*64 + i*16 + quad*4 + r;                              \
                xpb[buf][c][m] = (_Float16)(xacc[i][r] + xb2[i][r]);           \
            }                                                                  \
    }

        LOAD_X(0);
        #pragma unroll
        for (int kt = 0; kt < 4; ++kt) bx[kt] = cvt8(xr[kt][0], xr[kt][1]);
        #pragma unroll
        for (int i = 0; i < 4; ++i) xacc[i] = (f32x4){0,0,0,0};
        #pragma unroll
        for (int kt = 0; kt < 4; ++kt) XPROJ_PIECE(kt)
        XPROJ_WRITE(0);
        LOAD_X(1);
        asm volatile("s_waitcnt lgkmcnt(0) vmcnt(0)" ::: "memory");
        __builtin_amdgcn_s_barrier();

        for (int tb = 0; tb < TBLK2_; ++tb) {
            const int p = tb & 1;
            const bool gen = (tb < TBLK2_ - 1);
            if (gen) {
                #pragma unroll
                for (int kt = 0; kt < 4; ++kt) bx[kt] = cvt8(xr[kt][0], xr[kt][1]);
                #pragma unroll
                for (int i = 0; i < 4; ++i) xacc[i] = (f32x4){0,0,0,0};
            }
            __builtin_amdgcn_sched_barrier(0);
            BAR_LGKM();                                               // 1
            if (gen) { XPROJ_PIECE(0) }
            __builtin_amdgcn_sched_barrier(0);
            BAR_LGKM();                                               // 2
            if (gen) { XPROJ_PIECE(1) }
            __builtin_amdgcn_sched_barrier(0);
            BAR_LGKM();                                               // 3
            if (gen) { XPROJ_PIECE(2) }
            __builtin_amdgcn_sched_barrier(0);
            BAR_LGKM();                                               // 4
            if (gen) { XPROJ_PIECE(3) }
            __builtin_amdgcn_sched_barrier(0);
            BAR_LGKM();                                               // 5
            BAR_LGKM();                                               // 6
            if (gen) { XPROJ_WRITE(p ^ 1); }
            BAR_LGKM();                                               // 7
            if (tb < TBLK2_ - 2) { LOAD_X(tb + 2); }
            BAR_LGKM();                                               // 8
            BAR_LGKM();                                               // 9
            BAR_LGKM();                                               // 10
            BAR_LGKM();                                               // 11
            BAR_LGKM();                                               // 12
            BAR_LGKM();                                               // 13
            BAR_LGKM();                                               // 14
            BAR_LGKM();                                               // 15
            BAR_LGKM();                                               // 16
        }
#undef LOAD_X
#undef XPROJ_PIECE
#undef XPROJ_WRITE
    } else {
        // ================= out-projection consumer waves =================
        // Process block tb-1 during block tb; epilogue (barrier-free) does
        // the last block. A = 16 h-timesteps from hist, B = W_out cols.
        const int ow = wave - 12;                 // 0..3, owns out cols [ow*32, ow*32+32)
        const int wcol = ow * 32;

        h8 bo[2][8];
        #pragma unroll
        for (int t2 = 0; t2 < 2; ++t2)
            #pragma unroll
            for (int kt = 0; kt < 8; ++kt)
                bo[t2][kt] = ld_cvt8(w_out + (size_t)(wcol + t2*16 + n) * H_ + kt*32 + quad*8);

        float ob[2];
        #pragma unroll
        for (int t2 = 0; t2 < 2; ++t2) ob[t2] = b_out[wcol + t2*16 + n];

        asm volatile("s_waitcnt lgkmcnt(0) vmcnt(0)" ::: "memory");
        __builtin_amdgcn_s_barrier();

#define XO_PIECE(kt)                                                           \
    {                                                                          \
        oacc[0] = __builtin_amdgcn_mfma_f32_16x16x32_f16(av2[kt], bo[0][kt], oacc[0], 0, 0, 0); \
        oacc[1] = __builtin_amdgcn_mfma_f32_16x16x32_f16(av2[kt], bo[1][kt], oacc[1], 0, 0, 0); \
    }
#define XO_STORE(TP0)                                                          \
    {                                                                          \
        _Pragma("unroll")                                                      \
        for (int t2 = 0; t2 < 2; ++t2)                                         \
            _Pragma("unroll")                                                  \
            for (int r = 0; r < 4; ++r)                                        \
                out[((size_t)((TP0) + quad*4 + r) * B_ + b) * NOUT_ + wcol + t2*16 + n] = oacc[t2][r] + ob[t2]; \
    }

        for (int tb = 0; tb < TBLK2_; ++tb) {
            const int pp = (tb & 1) ^ 1;          // parity of block tb-1
            const bool run = (tb > 0);
            h8 av2[8];
            f32x4 oacc[2];
            if (run) {
                #pragma unroll
                for (int kt = 0; kt < 8; ++kt)
                    av2[kt] = *(const h8*)&hist[pp][n][kt*32 + quad*8];
                oacc[0] = (f32x4){0,0,0,0}; oacc[1] = (f32x4){0,0,0,0};
            }
            __builtin_amdgcn_sched_barrier(0);
            BAR_LGKM();                                               // 1
            if (run) { XO_PIECE(0) XO_PIECE(1) }
            __builtin_amdgcn_sched_barrier(0);
            BAR_LGKM();                                               // 2
            if (run) { XO_PIECE(2) XO_PIECE(3) }
            __builtin_amdgcn_sched_barrier(0);
            BAR_LGKM();                                               // 3
            if (run) { XO_PIECE(4) XO_PIECE(5) }
            __builtin_amdgcn_sched_barrier(0);
            BAR_LGKM();                                               // 4
            if (run) { XO_PIECE(6) XO_PIECE(7) }
            __builtin_amdgcn_sched_barrier(0);
            BAR_LGKM();                                               // 5
            BAR_LGKM();                                               // 6
            if (run) { XO_STORE((tb - 1) * 16) }
            BAR_LGKM();                                               // 7
            BAR_LGKM();                                               // 8
            BAR_LGKM();                                               // 9
            BAR_LGKM();                                               // 10
            BAR_LGKM();                                               // 11
            BAR_LGKM();                                               // 12
            BAR_LGKM();                                               // 13
            BAR_LGKM();                                               // 14
            BAR_LGKM();                                               // 15
            BAR_LGKM();                                               // 16
        }
        // epilogue: last block (parity (TBLK2_-1)&1), no barriers
        {
            const int pp = (TBLK2_ - 1) & 1;
            h8 av2[8];
            #pragma unroll
            for (int kt = 0; kt < 8; ++kt)
                av2[kt] = *(const h8*)&hist[pp][n][kt*32 + quad*8];
            f32x4 oacc[2];
            oacc[0] = (f32x4){0,0,0,0}; oacc[1] = (f32x4){0,0,0,0};
            #pragma unroll
            for (int kt = 0; kt < 8; ++kt) XO_PIECE(kt)
            XO_STORE((TBLK2_ - 1) * 16)
        }
#undef XO_PIECE
#undef XO_STORE
    }
}

extern "C" void kernel_launch(void* const* d_in, const int* in_sizes, int n_in,
                              void* d_out, int out_size, void* d_ws, size_t ws_size,
                              hipStream_t stream) {
    const float* x     = (const float*)d_in[0];
    const float* w_ih  = (const float*)d_in[1];
    const float* w_hh  = (const float*)d_in[2];
    const float* b_ih  = (const float*)d_in[3];
    const float* b_hh  = (const float*)d_in[4];
    const float* w_out = (const float*)d_in[5];
    const float* b_out = (const float*)d_in[6];

    k2_fused<<<B_, 1024, 0, stream>>>(x, w_ih, w_hh, b_ih, b_hh,
                                      w_out, b_out, (float*)d_out);
}

// Round 9
// 839.592 us; speedup vs baseline: 1.3686x; 1.0054x over previous
//
#include <hip/hip_runtime.h>
#include <hip/hip_bf16.h>
#include <hip/hip_fp16.h>

#define T_ 2048
#define B_ 64
#define NIN_ 128
#define H_ 256
#define NOUT_ 128
#define TB_ (T_*B_)
#define BH_ (B_*H_)
#define TBLK2_ (T_/16)   // 128 blocks of 16 timesteps

typedef _Float16 h8 __attribute__((ext_vector_type(8)));
typedef float f32x4 __attribute__((ext_vector_type(4)));

// LDS-only barrier: do NOT drain vmcnt (global loads/stores stay in flight).
#define BAR_LGKM() asm volatile("s_waitcnt lgkmcnt(0)\n\ts_barrier" ::: "memory")

__device__ __forceinline__ h8 cvt8(float4 a, float4 b) {
    h8 r;
    r[0] = (_Float16)a.x; r[1] = (_Float16)a.y; r[2] = (_Float16)a.z; r[3] = (_Float16)a.w;
    r[4] = (_Float16)b.x; r[5] = (_Float16)b.y; r[6] = (_Float16)b.z; r[7] = (_Float16)b.w;
    return r;
}
__device__ __forceinline__ h8 ld_cvt8(const float* __restrict__ p) {
    const float4* q = (const float4*)p;
    return cvt8(q[0], q[1]);
}

// tanh(x) = 1 - 2/(exp2(x*2*log2e)+1); fold the 2x into the exp2 constant.
__device__ __forceinline__ float tanh_fast(float sv) {
#if __has_builtin(__builtin_amdgcn_exp2f)
    float e = __builtin_amdgcn_exp2f(sv * 2.885390081777927f);   // 2*log2(e)
#else
    float e = __expf(2.0f * sv);
#endif
    return fmaf(-2.0f, __builtin_amdgcn_rcpf(e + 1.0f), 1.0f);
}

// ---------------------------------------------------------------------------
// FULLY FUSED RNN: one kernel, one WG per batch, 1024 threads = 16 waves
// (4/SIMD: 2 scan + 1 xproj-producer + 1 out-projection consumer).
//
// Round-9 deltas (serial-tail trim, structure frozen from round 8):
//   - hb eliminated: hist is the ONLY h-exchange. Scan step C reads
//     hist[p][C-1] (C=0: hist[p^1][15]) with the same quad-broadcast
//     pattern, writes hist[p][C]. One ds_write/step instead of two.
//   - tanh via exp2 with folded constant (one TRANS op on the tail).
//   - scan acc split into 2 chains per tile (depth 8 -> 4).
// Roles and barrier ladder identical to round 8 (1 prologue + 16/block).
// ---------------------------------------------------------------------------
__global__ __launch_bounds__(1024, 1) void k2_fused(
    const float* __restrict__ x,           // [T][B][NIN] f32
    const float* __restrict__ w_ih,        // [H][NIN] f32
    const float* __restrict__ w_hh,        // [H][H] f32
    const float* __restrict__ b_ih,
    const float* __restrict__ b_hh,
    const float* __restrict__ w_out,       // [NOUT][H] f32
    const float* __restrict__ b_out,
    float* __restrict__ out)               // [T][B][NOUT] f32
{
    const int tid = threadIdx.x;
    const int lane = tid & 63, wave = tid >> 6;   // 0..15
    const int n = lane & 15, quad = lane >> 4;
    const int b = blockIdx.x;

    __shared__ __align__(16) _Float16 xpb[2][256][24];   // [parity][col][t%16], stride 24
    __shared__ __align__(16) _Float16 hist[2][16][264];  // [parity][t%16][col], pad 264

    if (wave < 8) {
        // ================= scan waves =================
        const int tsel = quad & 1;
        const int j = wave*32 + tsel*16 + n;      // owned output column
        const bool writer = (quad < 2);           // quads 2,3 duplicate 0,1

        h8 bf[2][8];
        #pragma unroll
        for (int t = 0; t < 2; ++t)
            #pragma unroll
            for (int kt = 0; kt < 8; ++kt)
                bf[t][kt] = ld_cvt8(w_hh + (size_t)(wave*32 + t*16 + n) * H_ + kt*32 + quad*8);

        if (tid < 256) hist[1][15][tid] = (_Float16)0.0f;   // h(-1) = 0
        asm volatile("s_waitcnt lgkmcnt(0) vmcnt(0)" ::: "memory");
        __builtin_amdgcn_s_barrier();

#define K2_STEP(RPP, RC, C, XV)                                                \
    {                                                                          \
        h8 av[8];                                                              \
        _Pragma("unroll")                                                      \
        for (int kt = 0; kt < 8; ++kt)                                         \
            av[kt] = *(const h8*)&hist[RPP][RC][kt*32 + quad*8];               \
        f32x4 acc[2][2];                                                       \
        acc[0][0] = (f32x4){0,0,0,0}; acc[0][1] = (f32x4){0,0,0,0};            \
        acc[1][0] = (f32x4){0,0,0,0}; acc[1][1] = (f32x4){0,0,0,0};            \
        __builtin_amdgcn_s_setprio(1);                                         \
        _Pragma("unroll")                                                      \
        for (int kt = 0; kt < 8; ++kt) {                                       \
            acc[0][kt & 1] = __builtin_amdgcn_mfma_f32_16x16x32_f16(av[kt], bf[0][kt], acc[0][kt & 1], 0, 0, 0); \
            acc[1][kt & 1] = __builtin_amdgcn_mfma_f32_16x16x32_f16(av[kt], bf[1][kt], acc[1][kt & 1], 0, 0, 0); \
        }                                                                      \
        __builtin_amdgcn_s_setprio(0);                                         \
        float vv = tsel ? (acc[1][0][0] + acc[1][1][0])                        \
                        : (acc[0][0][0] + acc[0][1][0]);                       \
        float hn = tanh_fast(vv + (XV));                                       \
        _Float16 h16 = (_Float16)hn;                                           \
        if (writer) hist[p][C][j] = h16;                                       \
        BAR_LGKM();                                                            \
    }

        for (int tb = 0; tb < TBLK2_; ++tb) {
            const int p = tb & 1;
            h8 cur0 = *(const h8*)&xpb[p][j][0];
            K2_STEP(p ^ 1, 15, 0,  (float)cur0[0])
            K2_STEP(p,  0,  1,  (float)cur0[1])
            K2_STEP(p,  1,  2,  (float)cur0[2])
            K2_STEP(p,  2,  3,  (float)cur0[3])
            K2_STEP(p,  3,  4,  (float)cur0[4])
            K2_STEP(p,  4,  5,  (float)cur0[5])
            K2_STEP(p,  5,  6,  (float)cur0[6])
            K2_STEP(p,  6,  7,  (float)cur0[7])
            h8 cur1 = *(const h8*)&xpb[p][j][8];
            K2_STEP(p,  7,  8,  (float)cur1[0])
            K2_STEP(p,  8,  9,  (float)cur1[1])
            K2_STEP(p,  9,  10, (float)cur1[2])
            K2_STEP(p, 10, 11, (float)cur1[3])
            K2_STEP(p, 11, 12, (float)cur1[4])
            K2_STEP(p, 12, 13, (float)cur1[5])
            K2_STEP(p, 13, 14, (float)cur1[6])
            K2_STEP(p, 14, 15, (float)cur1[7])
        }
#undef K2_STEP
    } else if (wave < 12) {
        // ================= xproj producer waves =================
        const int w = wave - 8;                   // 0..3, owns cols [w*64, w*64+64)
        const int m = n;                          // timestep index within block

        h8 aih[4][4];
        #pragma unroll
        for (int i = 0; i < 4; ++i)
            #pragma unroll
            for (int kt = 0; kt < 4; ++kt)
                aih[i][kt] = ld_cvt8(w_ih + (size_t)(w*64 + i*16 + m) * NIN_ + kt*32 + quad*8);

        float xb2[4][4];
        #pragma unroll
        for (int i = 0; i < 4; ++i)
            #pragma unroll
            for (int r = 0; r < 4; ++r) {
                int c = w*64 + i*16 + quad*4 + r;
                xb2[i][r] = b_ih[c] + b_hh[c];
            }

        float4 xr[4][2];
        h8 bx[4];
        f32x4 xacc[4];

#define LOAD_X(blk)                                                            \
    {                                                                          \
        _Pragma("unroll")                                                      \
        for (int kt = 0; kt < 4; ++kt) {                                       \
            const float4* q = (const float4*)(x + ((size_t)((blk)*16 + m) * B_ + b) * NIN_ + kt*32 + quad*8); \
            xr[kt][0] = q[0]; xr[kt][1] = q[1];                                \
        }                                                                      \
    }

#define XPROJ_PIECE(kt)                                                        \
    {                                                                          \
        _Pragma("unroll")                                                      \
        for (int i = 0; i < 4; ++i)                                            \
            xacc[i] = __builtin_amdgcn_mfma_f32_16x16x32_f16(aih[i][kt], bx[kt], xacc[i], 0, 0, 0); \
    }

#define XPROJ_WRITE(buf)                                                       \
    {                                                                          \
        _Pragma("unroll")                                                      \
        for (int i = 0; i < 4; ++i)                                            \
            _Pragma("unroll")                                                  \
            for (int r = 0; r < 4; ++r) {                                      \
                int c = w*64 + i*16 + quad*4 + r;                              \
                xpb[buf][c][m] = (_Float16)(xacc[i][r] + xb2[i][r]);           \
            }                                                                  \
    }

        LOAD_X(0);
        #pragma unroll
        for (int kt = 0; kt < 4; ++kt) bx[kt] = cvt8(xr[kt][0], xr[kt][1]);
        #pragma unroll
        for (int i = 0; i < 4; ++i) xacc[i] = (f32x4){0,0,0,0};
        #pragma unroll
        for (int kt = 0; kt < 4; ++kt) XPROJ_PIECE(kt)
        XPROJ_WRITE(0);
        LOAD_X(1);
        asm volatile("s_waitcnt lgkmcnt(0) vmcnt(0)" ::: "memory");
        __builtin_amdgcn_s_barrier();

        for (int tb = 0; tb < TBLK2_; ++tb) {
            const int p = tb & 1;
            const bool gen = (tb < TBLK2_ - 1);
            if (gen) {
                #pragma unroll
                for (int kt = 0; kt < 4; ++kt) bx[kt] = cvt8(xr[kt][0], xr[kt][1]);
                #pragma unroll
                for (int i = 0; i < 4; ++i) xacc[i] = (f32x4){0,0,0,0};
            }
            __builtin_amdgcn_sched_barrier(0);
            BAR_LGKM();                                               // 1
            if (gen) { XPROJ_PIECE(0) }
            __builtin_amdgcn_sched_barrier(0);
            BAR_LGKM();                                               // 2
            if (gen) { XPROJ_PIECE(1) }
            __builtin_amdgcn_sched_barrier(0);
            BAR_LGKM();                                               // 3
            if (gen) { XPROJ_PIECE(2) }
            __builtin_amdgcn_sched_barrier(0);
            BAR_LGKM();                                               // 4
            if (gen) { XPROJ_PIECE(3) }
            __builtin_amdgcn_sched_barrier(0);
            BAR_LGKM();                                               // 5
            BAR_LGKM();                                               // 6
            if (gen) { XPROJ_WRITE(p ^ 1); }
            BAR_LGKM();                                               // 7
            if (tb < TBLK2_ - 2) { LOAD_X(tb + 2); }
            BAR_LGKM();                                               // 8
            BAR_LGKM();                                               // 9
            BAR_LGKM();                                               // 10
            BAR_LGKM();                                               // 11
            BAR_LGKM();                                               // 12
            BAR_LGKM();                                               // 13
            BAR_LGKM();                                               // 14
            BAR_LGKM();                                               // 15
            BAR_LGKM();                                               // 16
        }
#undef LOAD_X
#undef XPROJ_PIECE
#undef XPROJ_WRITE
    } else {
        // ================= out-projection consumer waves =================
        const int ow = wave - 12;                 // 0..3, owns out cols [ow*32, ow*32+32)
        const int wcol = ow * 32;

        h8 bo[2][8];
        #pragma unroll
        for (int t2 = 0; t2 < 2; ++t2)
            #pragma unroll
            for (int kt = 0; kt < 8; ++kt)
                bo[t2][kt] = ld_cvt8(w_out + (size_t)(wcol + t2*16 + n) * H_ + kt*32 + quad*8);

        float ob[2];
        #pragma unroll
        for (int t2 = 0; t2 < 2; ++t2) ob[t2] = b_out[wcol + t2*16 + n];

        asm volatile("s_waitcnt lgkmcnt(0) vmcnt(0)" ::: "memory");
        __builtin_amdgcn_s_barrier();

#define XO_PIECE(kt)                                                           \
    {                                                                          \
        oacc[0] = __builtin_amdgcn_mfma_f32_16x16x32_f16(av2[kt], bo[0][kt], oacc[0], 0, 0, 0); \
        oacc[1] = __builtin_amdgcn_mfma_f32_16x16x32_f16(av2[kt], bo[1][kt], oacc[1], 0, 0, 0); \
    }
#define XO_STORE(TP0)                                                          \
    {                                                                          \
        _Pragma("unroll")                                                      \
        for (int t2 = 0; t2 < 2; ++t2)                                         \
            _Pragma("unroll")                                                  \
            for (int r = 0; r < 4; ++r)                                        \
                out[((size_t)((TP0) + quad*4 + r) * B_ + b) * NOUT_ + wcol + t2*16 + n] = oacc[t2][r] + ob[t2]; \
    }

        for (int tb = 0; tb < TBLK2_; ++tb) {
            const int pp = (tb & 1) ^ 1;          // parity of block tb-1
            const bool run = (tb > 0);
            h8 av2[8];
            f32x4 oacc[2];
            if (run) {
                #pragma unroll
                for (int kt = 0; kt < 8; ++kt)
                    av2[kt] = *(const h8*)&hist[pp][n][kt*32 + quad*8];
                oacc[0] = (f32x4){0,0,0,0}; oacc[1] = (f32x4){0,0,0,0};
            }
            __builtin_amdgcn_sched_barrier(0);
            BAR_LGKM();                                               // 1
            if (run) { XO_PIECE(0) XO_PIECE(1) }
            __builtin_amdgcn_sched_barrier(0);
            BAR_LGKM();                                               // 2
            if (run) { XO_PIECE(2) XO_PIECE(3) }
            __builtin_amdgcn_sched_barrier(0);
            BAR_LGKM();                                               // 3
            if (run) { XO_PIECE(4) XO_PIECE(5) }
            __builtin_amdgcn_sched_barrier(0);
            BAR_LGKM();                                               // 4
            if (run) { XO_PIECE(6) XO_PIECE(7) }
            __builtin_amdgcn_sched_barrier(0);
            BAR_LGKM();                                               // 5
            BAR_LGKM();                                               // 6
            if (run) { XO_STORE((tb - 1) * 16) }
            BAR_LGKM();                                               // 7
            BAR_LGKM();                                               // 8
            BAR_LGKM();                                               // 9
            BAR_LGKM();                                               // 10
            BAR_LGKM();                                               // 11
            BAR_LGKM();                                               // 12
            BAR_LGKM();                                               // 13
            BAR_LGKM();                                               // 14
            BAR_LGKM();                                               // 15
            BAR_LGKM();                                               // 16
        }
        // epilogue: last block (parity (TBLK2_-1)&1), no barriers
        {
            const int pp = (TBLK2_ - 1) & 1;
            h8 av2[8];
            #pragma unroll
            for (int kt = 0; kt < 8; ++kt)
                av2[kt] = *(const h8*)&hist[pp][n][kt*32 + quad*8];
            f32x4 oacc[2];
            oacc[0] = (f32x4){0,0,0,0}; oacc[1] = (f32x4){0,0,0,0};
            #pragma unroll
            for (int kt = 0; kt < 8; ++kt) XO_PIECE(kt)
            XO_STORE((TBLK2_ - 1) * 16)
        }
#undef XO_PIECE
#undef XO_STORE
    }
}

extern "C" void kernel_launch(void* const* d_in, const int* in_sizes, int n_in,
                              void* d_out, int out_size, void* d_ws, size_t ws_size,
                              hipStream_t stream) {
    const float* x     = (const float*)d_in[0];
    const float* w_ih  = (const float*)d_in[1];
    const float* w_hh  = (const float*)d_in[2];
    const float* b_ih  = (const float*)d_in[3];
    const float* b_hh  = (const float*)d_in[4];
    const float* w_out = (const float*)d_in[5];
    const float* b_out = (const float*)d_in[6];

    k2_fused<<<B_, 1024, 0, stream>>>(x, w_ih, w_hh, b_ih, b_hh,
                                      w_out, b_out, (float*)d_out);
}